// Round 13
// baseline (231.687 us; speedup 1.0000x reference)
//
#include <hip/hip_runtime.h>
#include <hip/hip_bf16.h>

// MHA forward: b=2, t=2048, d=1024, h=16, n=64. Inputs/outputs FLOAT32.
// bf16 internals. ws layout unchanged (kb/qb/vb/Wob slots now unused;
// Op still aliases kb): kb|qb|vb (4194304 ea) | Wkb|Wqb|Wvb|Wob (1048576
// ea) | Kp|Qp|Vt (4194304 ea).
// Round 13 = round-12 RESUBMIT (round-12 bench was a container-acquisition
// infra failure, same as round 3; code re-audited: bounds, LDS dest
// equivalence to DMA rule, pack order, barrier hazards all verified).
// Change vs round-8/11 base (208.7/209.5 us): fused activation convert —
// proj3 reads k/q/v FLOAT32 directly, converting during A-operand staging
// (float4 loads issued pre-barrier -> cvt -> ds_write_b128 to the SAME
// linear LDS offset the DMA used; source uses the SAME scol swizzle map,
// so the proven read-side algebra is untouched). out_gemm converts Wo
// inline the same way on its B operand. convert kernel shrinks to the
// 3 proj weights only (~19 MB, ~3 us; was ~100 MB, ~16 us). Numerics
// identical (__float22bfloat162_rn everywhere). attn v11 byte-identical.

typedef unsigned short u16;
typedef unsigned int   u32;
using short8 = __attribute__((ext_vector_type(8))) short;
using f32x4  = __attribute__((ext_vector_type(4))) float;

__device__ __forceinline__ u16 f2b(float f) {
    u32 u = __float_as_uint(f);
    u += 0x7FFFu + ((u >> 16) & 1u);
    return (u16)(u >> 16);
}
__device__ __forceinline__ u32 pack2(float lo, float hi) {
    union { __hip_bfloat162 h; u32 u; } c;
    c.h = __float22bfloat162_rn(make_float2(lo, hi));
    return c.u;
}
__device__ __forceinline__ float fexp2(float x) {
    return __builtin_amdgcn_exp2f(x);
}
__device__ __forceinline__ void gld_lds16(const u16* g, u16* l) {
    __builtin_amdgcn_global_load_lds(
        (const __attribute__((address_space(1))) void*)g,
        (__attribute__((address_space(3))) void*)l, 16, 0, 0);
}

// ---------------------------------------------------------------------------
// fp32 -> bf16 convert, proj weights only (Wk, Wq, Wv). grid (256, 3).
// ---------------------------------------------------------------------------
__global__ __launch_bounds__(256) void convert_w_kernel(
    const float* s0, const float* s1, const float* s2,
    u16* d0, u16* d1, u16* d2)
{
    const int y = blockIdx.y;
    const float* s = (y == 0) ? s0 : ((y == 1) ? s1 : s2);
    u16*         d = (y == 0) ? d0 : ((y == 1) ? d1 : d2);
    for (u32 i = blockIdx.x * 256 + threadIdx.x; i < 262144; i += 256 * 256) {
        float4 f = ((const float4*)s)[i];
        uint2 o; o.x = pack2(f.x, f.y); o.y = pack2(f.z, f.w);
        ((uint2*)d)[i] = o;
    }
}

// ---------------------------------------------------------------------------
// GEMM core: C(128x128) = A[m][k] @ B[n][k]^T, K=1024, bf16 MFMA, 2-barrier
// K-loop, XOR-swizzled unpadded LDS (round-5-proven read algebra).
// AF32/BF32: that operand is FLOAT32 in global; staged via reg (float4 x2
// pre-barrier) + cvt + ds_write_b128 to the SAME linear LDS offset the DMA
// would use (wave base + lane*16B), source at the SAME scol element map.
// Otherwise staged via global_load_lds exactly as before.
// MODE 0: u16 C row-major (scaled). MODE 3: u16 C in Vt layout.
// ---------------------------------------------------------------------------
template <int MODE, int AF32, int BF32>
__device__ __forceinline__ void gemm_core(
    const void* __restrict__ Av, const void* __restrict__ Bv,
    void* __restrict__ C, float scale, u32 bm, u32 bn)
{
    constexpr u32 K = 1024;
    __shared__ u16 As[128 * 32];
    __shared__ u16 Bs[128 * 32];

    const int tid  = threadIdx.x;
    const int lane = tid & 63;
    const int w    = tid >> 6;
    const int wr   = w >> 1, wc = w & 1;
    const int ml   = lane & 15, g = lane >> 4;

    f32x4 acc[4][4] = {};

    const u32 srow = w * 32 + (lane >> 2);
    const u32 scol = (u32)(((lane & 3) ^ ((lane >> 3) & 3)) * 8);
    const u16*   gA  = (const u16*)Av   + (size_t)(bm + srow) * K + scol;
    const float* gAf = (const float*)Av + (size_t)(bm + srow) * K + scol;
    const u16*   gB  = (const u16*)Bv   + (size_t)(bn + srow) * K + scol;
    const float* gBf = (const float*)Bv + (size_t)(bn + srow) * K + scol;
    u16* lA  = &As[w * 1024];
    u16* lB  = &Bs[w * 1024];
    u16* lAw = &As[w * 1024 + (u32)(lane * 8)];   // explicit dest == DMA dest
    u16* lBw = &Bs[w * 1024 + (u32)(lane * 8)];

    const u32 fsw = (u32)((g ^ ((ml >> 1) & 3)) * 8);

    for (u32 k0 = 0; k0 < K; k0 += 32) {
        float4 av4[4], bv4[4];
        if constexpr (AF32) {
            av4[0] = *(const float4*)(gAf + k0);
            av4[1] = *(const float4*)(gAf + k0 + 4);
            av4[2] = *(const float4*)(gAf + 16 * K + k0);
            av4[3] = *(const float4*)(gAf + 16 * K + k0 + 4);
        }
        if constexpr (BF32) {
            bv4[0] = *(const float4*)(gBf + k0);
            bv4[1] = *(const float4*)(gBf + k0 + 4);
            bv4[2] = *(const float4*)(gBf + 16 * K + k0);
            bv4[3] = *(const float4*)(gBf + 16 * K + k0 + 4);
        }
        __syncthreads();
        if constexpr (AF32) {
            uint4 p0, p1;
            p0.x = pack2(av4[0].x, av4[0].y); p0.y = pack2(av4[0].z, av4[0].w);
            p0.z = pack2(av4[1].x, av4[1].y); p0.w = pack2(av4[1].z, av4[1].w);
            p1.x = pack2(av4[2].x, av4[2].y); p1.y = pack2(av4[2].z, av4[2].w);
            p1.z = pack2(av4[3].x, av4[3].y); p1.w = pack2(av4[3].z, av4[3].w);
            *(uint4*)lAw = p0;
            *(uint4*)(lAw + 512) = p1;
        } else {
            gld_lds16(gA + k0, lA);
            gld_lds16(gA + 16 * K + k0, lA + 512);
        }
        if constexpr (BF32) {
            uint4 p0, p1;
            p0.x = pack2(bv4[0].x, bv4[0].y); p0.y = pack2(bv4[0].z, bv4[0].w);
            p0.z = pack2(bv4[1].x, bv4[1].y); p0.w = pack2(bv4[1].z, bv4[1].w);
            p1.x = pack2(bv4[2].x, bv4[2].y); p1.y = pack2(bv4[2].z, bv4[2].w);
            p1.z = pack2(bv4[3].x, bv4[3].y); p1.w = pack2(bv4[3].z, bv4[3].w);
            *(uint4*)lBw = p0;
            *(uint4*)(lBw + 512) = p1;
        } else {
            gld_lds16(gB + k0, lB);
            gld_lds16(gB + 16 * K + k0, lB + 512);
        }
        __syncthreads();

        short8 af[4], bf[4];
#pragma unroll
        for (int it = 0; it < 4; ++it)
            af[it] = *(const short8*)&As[(wr * 64 + it * 16 + ml) * 32 + fsw];
#pragma unroll
        for (int ct = 0; ct < 4; ++ct)
            bf[ct] = *(const short8*)&Bs[(wc * 64 + ct * 16 + ml) * 32 + fsw];
#pragma unroll
        for (int it = 0; it < 4; ++it)
#pragma unroll
            for (int ct = 0; ct < 4; ++ct)
                acc[it][ct] = __builtin_amdgcn_mfma_f32_16x16x32_bf16(
                    af[it], bf[ct], acc[it][ct], 0, 0, 0);
    }

    if (MODE == 3) {
#pragma unroll
        for (int ct = 0; ct < 4; ++ct) {
            const u32 col = bn + wc * 64 + ct * 16 + ml;
            u16* dst = (u16*)C + (col >> 11) * 2097152 + (col & 2047);
#pragma unroll
            for (int it = 0; it < 4; ++it) {
                const u32 row = bm + wr * 64 + it * 16 + g * 4;
#pragma unroll
                for (int r = 0; r < 4; ++r)
                    dst[(size_t)(row + r) * 2048] = f2b(acc[it][ct][r]);
            }
        }
    } else {
#pragma unroll
        for (int ct = 0; ct < 4; ++ct) {
            const u32 col = bn + wc * 64 + ct * 16 + ml;
#pragma unroll
            for (int it = 0; it < 4; ++it) {
                const u32 row = bm + wr * 64 + it * 16 + g * 4;
#pragma unroll
                for (int r = 0; r < 4; ++r)
                    ((u16*)C)[(size_t)(row + r) * 1024 + col] =
                        f2b(acc[it][ct][r] * scale);
            }
        }
    }
}

__global__ __launch_bounds__(256) void proj3_kernel(
    const float* kin, const float* qin, const float* vin,
    const u16* Wkb, const u16* Wqb, const u16* Wvb,
    u16* Kp, u16* Qp, u16* Vt)
{
    if (blockIdx.z == 0)
        gemm_core<0, 1, 0>(kin, Wkb, Kp, 1.0f, blockIdx.y * 128, blockIdx.x * 128);
    else if (blockIdx.z == 1)
        gemm_core<0, 1, 0>(qin, Wqb, Qp, 0.18033688011112042f, blockIdx.y * 128, blockIdx.x * 128);
    else
        gemm_core<3, 0, 1>(Wvb, vin, Vt, 1.0f, blockIdx.x * 128, blockIdx.y * 128);
}

// ---------------------------------------------------------------------------
// OUT GEMM: 64x128 tile, grid (8, 64) = 512 blocks (2/CU). A = Op (bf16,
// DMA-staged as before); B = Wo FLOAT32, reg-staged + cvt inline (same
// pattern as proj3's A path). Wave w: rows (w>>1)*32..+31, cols
// (w&1)*64..+63 -> acc[2][4].
// ---------------------------------------------------------------------------
__global__ __launch_bounds__(256) void out_gemm_kernel(
    const u16* __restrict__ A, const float* __restrict__ W,
    float* __restrict__ C, const float* __restrict__ bias)
{
    constexpr u32 K = 1024;
    __shared__ u16 As[64 * 32];
    __shared__ u16 Bs[128 * 32];

    const int tid  = threadIdx.x;
    const int lane = tid & 63;
    const int w    = tid >> 6;
    const int wr   = w >> 1, wc = w & 1;
    const int ml   = lane & 15, g = lane >> 4;
    const u32 bm   = blockIdx.y * 64, bn = blockIdx.x * 128;

    f32x4 acc[2][4] = {};

    const u32 scol = (u32)(((lane & 3) ^ ((lane >> 3) & 3)) * 8);
    const u16*   gA  = A + (size_t)(bm + w * 16 + (lane >> 2)) * K + scol;
    const float* gBf = W + (size_t)(bn + w * 32 + (lane >> 2)) * K + scol;
    u16* lA  = &As[w * 512];
    u16* lBw = &Bs[w * 1024 + (u32)(lane * 8)];

    const u32 fsw = (u32)((g ^ ((ml >> 1) & 3)) * 8);

    for (u32 k0 = 0; k0 < K; k0 += 32) {
        float4 bv4[4];
        bv4[0] = *(const float4*)(gBf + k0);
        bv4[1] = *(const float4*)(gBf + k0 + 4);
        bv4[2] = *(const float4*)(gBf + 16 * K + k0);
        bv4[3] = *(const float4*)(gBf + 16 * K + k0 + 4);
        __syncthreads();
        gld_lds16(gA + k0, lA);
        {
            uint4 p0, p1;
            p0.x = pack2(bv4[0].x, bv4[0].y); p0.y = pack2(bv4[0].z, bv4[0].w);
            p0.z = pack2(bv4[1].x, bv4[1].y); p0.w = pack2(bv4[1].z, bv4[1].w);
            p1.x = pack2(bv4[2].x, bv4[2].y); p1.y = pack2(bv4[2].z, bv4[2].w);
            p1.z = pack2(bv4[3].x, bv4[3].y); p1.w = pack2(bv4[3].z, bv4[3].w);
            *(uint4*)lBw = p0;
            *(uint4*)(lBw + 512) = p1;
        }
        __syncthreads();

        short8 af[2], bf[4];
#pragma unroll
        for (int it = 0; it < 2; ++it)
            af[it] = *(const short8*)&As[(wr * 32 + it * 16 + ml) * 32 + fsw];
#pragma unroll
        for (int ct = 0; ct < 4; ++ct)
            bf[ct] = *(const short8*)&Bs[(wc * 64 + ct * 16 + ml) * 32 + fsw];
#pragma unroll
        for (int it = 0; it < 2; ++it)
#pragma unroll
            for (int ct = 0; ct < 4; ++ct)
                acc[it][ct] = __builtin_amdgcn_mfma_f32_16x16x32_bf16(
                    af[it], bf[ct], acc[it][ct], 0, 0, 0);
    }

#pragma unroll
    for (int ct = 0; ct < 4; ++ct) {
        const u32 col = bn + wc * 64 + ct * 16 + ml;
        const float bv = bias ? bias[col] : 0.0f;
#pragma unroll
        for (int it = 0; it < 2; ++it) {
            const u32 row = bm + wr * 32 + it * 16 + g * 4;
#pragma unroll
            for (int r = 0; r < 4; ++r)
                C[(size_t)(row + r) * 1024 + col] = acc[it][ct][r] + bv;
        }
    }
}

// ---------------------------------------------------------------------------
// Flash attention v11 (round-8 proven, 49.9 us): 128-q blocks, 8 waves,
// double-buffered K/V DMA, bijective XCD swizzle, setprio(1) around compute.
// BYTE-IDENTICAL to rounds 8/11.
// ---------------------------------------------------------------------------
__global__ __launch_bounds__(512, 4) void attn_kernel(
    const u16* __restrict__ Qp, const u16* __restrict__ Kp,
    const u16* __restrict__ Vt, u16* __restrict__ Op)
{
    __shared__ u16   Ks[2 * 4096];   // dbuf x [64 s][64 d], 16 KB
    __shared__ u16   Vs[2 * 4096];   // dbuf x [64 d][64 s], 16 KB
    __shared__ u16   Ps[8 * 1280];   // per-wave 32 q x (32 s + 8 pad), 20 KB
    __shared__ float Ls[4][32];

    const int tid  = threadIdx.x;
    const int lane = tid & 63;
    const int w    = tid >> 6;        // 0..7
    const int wq   = w >> 1;          // q-quarter owner (32 rows)
    const int ws   = w & 1;           // s-half of each 64-s step
    const int ml   = lane & 15;
    const int g    = lane >> 4;

    const u32 fid  = blockIdx.x + (blockIdx.y << 4);
    const u32 swz  = (fid & 7) * 64 + (fid >> 3);
    const u32 bh   = swz >> 4;
    const u32 t0   = (swz & 15) * 128;
    const u32 b    = bh >> 4, h = bh & 15;

    const u32 base  = b * 2048 * 1024 + h * 64;
    const u32 vbase = bh * 64 * 2048;

    short8 bq[2][2];
#pragma unroll
    for (int qt = 0; qt < 2; ++qt) {
        const u16* qr = Qp + base + (t0 + wq * 32 + qt * 16 + ml) * 1024 + g * 8;
        bq[qt][0] = *(const short8*)qr;
        bq[qt][1] = *(const short8*)(qr + 32);
    }

    f32x4 oacc[4][2] = {};
    float l4[2] = {};

    const u32 srow = (u32)(lane >> 3);
    const u32 schk = (u32)((lane & 7) ^ (lane >> 3));
    const u16* gK = Kp + base + (size_t)(w * 8 + srow) * 1024 + schk * 8;
    const u16* gV = Vt + vbase + (size_t)(w * 8 + srow) * 2048 + schk * 8;
    u16* lK0 = &Ks[w * 512];
    u16* lK1 = &Ks[4096 + w * 512];
    u16* lV0 = &Vs[w * 512];
    u16* lV1 = &Vs[4096 + w * 512];

    const u32 kaOff = (u32)((ws * 32 + ml) * 64 + ((g ^ (ml & 7)) * 8));
    const u32 vaOff = (u32)(ml * 64 + (((ws * 4 + g) ^ (ml & 7)) * 8));
    u16* Pw  = &Ps[w * 1280];
    u32* PwU = (u32*)Pw;
    const u32 pWr = (u32)(ml * 20 + g * 2);    // + qt*320 + sub*8   (u32)
    const u32 pRd = (u32)(ml * 40 + g * 8);    // + qt*640           (u16)

#define ATTN_STAGE(KD, VD)                                                   \
    { gld_lds16(gK, (KD)); gld_lds16(gV, (VD)); gK += 65536; gV += 64; }

#define ATTN_COMPUTE(KB, VB)                                                 \
    {                                                                        \
        __builtin_amdgcn_s_setprio(1);                                       \
        short8 vv[4];                                                        \
        _Pragma("unroll")                                                    \
        for (int dt = 0; dt < 4; ++dt)                                       \
            vv[dt] = *(const short8*)&(VB)[vaOff + dt * 1024];               \
        _Pragma("unroll")                                                    \
        for (int sub = 0; sub < 2; ++sub) {                                  \
            short8 k0 = *(const short8*)&(KB)[kaOff + sub * 1024];           \
            short8 k1 = *(const short8*)&(KB)[(kaOff ^ 32) + sub * 1024];    \
            _Pragma("unroll")                                                \
            for (int qt = 0; qt < 2; ++qt) {                                 \
                f32x4 z = {};                                                \
                z = __builtin_amdgcn_mfma_f32_16x16x32_bf16(                 \
                    k0, bq[qt][0], z, 0, 0, 0);                              \
                z = __builtin_amdgcn_mfma_f32_16x16x32_bf16(                 \
                    k1, bq[qt][1], z, 0, 0, 0);                              \
                const float p0 = fexp2(z[0]), p1 = fexp2(z[1]);              \
                const float p2 = fexp2(z[2]), p3 = fexp2(z[3]);              \
                l4[qt] += (p0 + p1) + (p2 + p3);                             \
                uint2 pv; pv.x = pack2(p0, p1); pv.y = pack2(p2, p3);        \
                *(uint2*)&PwU[pWr + (u32)(qt * 320 + sub * 8)] = pv;         \
            }                                                                \
        }                                                                    \
        _Pragma("unroll")                                                    \
        for (int qt = 0; qt < 2; ++qt) {                                     \
            short8 pb = *(const short8*)&Pw[pRd + (u32)(qt * 640)];          \
            _Pragma("unroll")                                                \
            for (int dt = 0; dt < 4; ++dt)                                   \
                oacc[dt][qt] = __builtin_amdgcn_mfma_f32_16x16x32_bf16(      \
                    vv[dt], pb, oacc[dt][qt], 0, 0, 0);                      \
        }                                                                    \
        __builtin_amdgcn_s_setprio(0);                                       \
    }

    ATTN_STAGE(lK0, lV0)
    __syncthreads();

#pragma unroll 1
    for (int it = 0; it < 16; ++it) {
        ATTN_STAGE(lK1, lV1)
        ATTN_COMPUTE(Ks, Vs)
        __syncthreads();
        if (it < 15) ATTN_STAGE(lK0, lV0)
        ATTN_COMPUTE(Ks + 4096, Vs + 4096)
        __syncthreads();
    }
#undef ATTN_STAGE
#undef ATTN_COMPUTE

#pragma unroll
    for (int qt = 0; qt < 2; ++qt) {
        l4[qt] += __shfl_xor(l4[qt], 16);
        l4[qt] += __shfl_xor(l4[qt], 32);
    }

    float* Rw = (wq < 2) ? ((float*)Ks + wq * 2048) : ((float*)Vs + (wq - 2) * 2048);
    if (ws == 1) {
#pragma unroll
        for (int dt = 0; dt < 4; ++dt)
#pragma unroll
            for (int qt = 0; qt < 2; ++qt)
#pragma unroll
                for (int r = 0; r < 4; ++r)
                    Rw[(dt * 16 + g * 4 + r) * 32 + qt * 16 + ml] = oacc[dt][qt][r];
        if (g == 0) {
#pragma unroll
            for (int qt = 0; qt < 2; ++qt) Ls[wq][qt * 16 + ml] = l4[qt];
        }
    }
    __syncthreads();
    if (ws == 0) {
#pragma unroll
        for (int dt = 0; dt < 4; ++dt)
#pragma unroll
            for (int qt = 0; qt < 2; ++qt)
#pragma unroll
                for (int r = 0; r < 4; ++r)
                    oacc[dt][qt][r] += Rw[(dt * 16 + g * 4 + r) * 32 + qt * 16 + ml];
#pragma unroll
        for (int qt = 0; qt < 2; ++qt) {
            const u32 q = (u32)(wq * 32 + qt * 16 + ml);
            const float inv = 1.0f / (l4[qt] + Ls[wq][qt * 16 + ml]);
            const u32 row = (b * 2048 + t0 + q) * 1024 + h * 64;
#pragma unroll
            for (int dt = 0; dt < 4; ++dt) {
                const u32 ci = row + dt * 16 + g * 4;
                *(u32*)&Op[ci]     = pack2(oacc[dt][qt][0] * inv, oacc[dt][qt][1] * inv);
                *(u32*)&Op[ci + 2] = pack2(oacc[dt][qt][2] * inv, oacc[dt][qt][3] * inv);
            }
        }
    }
}

extern "C" void kernel_launch(void* const* d_in, const int* in_sizes, int n_in,
                              void* d_out, int out_size, void* d_ws, size_t ws_size,
                              hipStream_t stream)
{
    const float* kin = (const float*)d_in[0];
    const float* qin = (const float*)d_in[1];
    const float* vin = (const float*)d_in[2];
    const float* Wk  = (const float*)d_in[3];
    const float* Wq  = (const float*)d_in[4];
    const float* Wv  = (const float*)d_in[5];
    const float* Wo  = (const float*)d_in[6];
    const float* bo  = (const float*)d_in[7];
    float* out = (float*)d_out;

    const size_t ACT = 4194304;
    const size_t WSZ = 1048576;

    u16* kb  = (u16*)d_ws;          // unused slot (Op home)
    u16* qb  = kb + ACT;            // unused
    u16* vb  = qb + ACT;            // unused
    u16* Wkb = vb + ACT;
    u16* Wqb = Wkb + WSZ;
    u16* Wvb = Wqb + WSZ;
    u16* Wob = Wvb + WSZ;           // unused
    u16* Kp  = Wob + WSZ;
    u16* Qp  = Kp + ACT;
    u16* Vt  = Qp + ACT;
    u16* Op  = kb;

    convert_w_kernel<<<dim3(256, 3), 256, 0, stream>>>(
        Wk, Wq, Wv, Wkb, Wqb, Wvb);
    proj3_kernel<<<dim3(8, 32, 3), 256, 0, stream>>>(
        kin, qin, vin, Wkb, Wqb, Wvb, Kp, Qp, Vt);
    attn_kernel<<<dim3(16, 32), 512, 0, stream>>>(Qp, Kp, Vt, Op);
    out_gemm_kernel<<<dim3(8, 64), 256, 0, stream>>>(Op, Wo, out, bo);
}

// Round 14
// 208.234 us; speedup vs baseline: 1.1126x; 1.1126x over previous
//
#include <hip/hip_runtime.h>
#include <hip/hip_bf16.h>

// MHA forward: b=2, t=2048, d=1024, h=16, n=64. Inputs/outputs FLOAT32.
// bf16 internals. ws (u16, 58.7 MB, proven): kb|qb|vb (4194304 ea) |
// Wkb|Wqb|Wvb|Wob (1048576 ea) | Kp|Qp|Vt (4194304 ea) | Op aliases kb.
// Round 14 = exact round-8/11 restore (verified twice: 208.7 / 209.5 us).
// Session evidence: five GEMM-side attacks all regressed vs this base —
// R6 dbuf+swizzle (+11), R7 split-K+atomics (+27), R9 256^2 retile (+9.4,
// 192-block underfill), R10 BK=64 (+5.7), R13 fused f32 convert (+23:
// staging traffic scales with tile-reuse factor; f32 operand re-read 8x
// = +190 MB FETCH — pre-converting to bf16 IS the bandwidth optimization).
// attn v11: 128-q blocks, 8 waves, dbuf K/V DMA via global_load_lds,
// bijective XCD swizzle, s_setprio(1) around compute = 49.9 us.

typedef unsigned short u16;
typedef unsigned int   u32;
using short8 = __attribute__((ext_vector_type(8))) short;
using f32x4  = __attribute__((ext_vector_type(4))) float;

__device__ __forceinline__ u16 f2b(float f) {
    u32 u = __float_as_uint(f);
    u += 0x7FFFu + ((u >> 16) & 1u);
    return (u16)(u >> 16);
}
__device__ __forceinline__ u32 pack2(float lo, float hi) {
    union { __hip_bfloat162 h; u32 u; } c;
    c.h = __float22bfloat162_rn(make_float2(lo, hi));
    return c.u;
}
__device__ __forceinline__ float fexp2(float x) {
    return __builtin_amdgcn_exp2f(x);
}
__device__ __forceinline__ void gld_lds16(const u16* g, u16* l) {
    __builtin_amdgcn_global_load_lds(
        (const __attribute__((address_space(1))) void*)g,
        (__attribute__((address_space(3))) void*)l, 16, 0, 0);
}

// ---------------------------------------------------------------------------
// fp32 -> bf16 convert. grid (1024, 7).
// ---------------------------------------------------------------------------
__global__ __launch_bounds__(256) void convert_kernel(
    const float* s0, const float* s1, const float* s2, const float* s3,
    const float* s4, const float* s5, const float* s6,
    u16* d0, u16* d1, u16* d2, u16* d3, u16* d4, u16* d5, u16* d6)
{
    const int y = blockIdx.y;
    const float* s; u16* d; u32 n;
    switch (y) {
        case 0: s = s0; d = d0; n = 1048576; break;
        case 1: s = s1; d = d1; n = 1048576; break;
        case 2: s = s2; d = d2; n = 1048576; break;
        case 3: s = s3; d = d3; n = 262144; break;
        case 4: s = s4; d = d4; n = 262144; break;
        case 5: s = s5; d = d5; n = 262144; break;
        default: s = s6; d = d6; n = 262144; break;
    }
    for (u32 i = blockIdx.x * 256 + threadIdx.x; i < n; i += 256 * 1024) {
        float4 f = ((const float4*)s)[i];
        uint2 o; o.x = pack2(f.x, f.y); o.y = pack2(f.z, f.w);
        ((uint2*)d)[i] = o;
    }
}

// ---------------------------------------------------------------------------
// GEMM core (round-5 proven): C(128x128) = A[m][k] @ B[n][k]^T, K=1024, bf16,
// 2-barrier global_load_lds K-loop, XOR-swizzled unpadded LDS.
// MODE 0: u16 C row-major. MODE 2: f32 C + bias. MODE 3: u16 C in Vt layout.
// ---------------------------------------------------------------------------
template <int MODE>
__device__ __forceinline__ void gemm_core(
    const u16* __restrict__ A, const u16* __restrict__ B,
    void* __restrict__ C, const float* __restrict__ bias, float scale,
    u32 bm, u32 bn)
{
    constexpr u32 K = 1024;
    __shared__ u16 As[128 * 32];
    __shared__ u16 Bs[128 * 32];

    const int tid  = threadIdx.x;
    const int lane = tid & 63;
    const int w    = tid >> 6;
    const int wr   = w >> 1, wc = w & 1;
    const int ml   = lane & 15, g = lane >> 4;

    f32x4 acc[4][4] = {};

    const u32 srow = w * 32 + (lane >> 2);
    const u32 scol = (u32)(((lane & 3) ^ ((lane >> 3) & 3)) * 8);
    const u16* gA = A + (size_t)(bm + srow) * K + scol;
    const u16* gB = B + (size_t)(bn + srow) * K + scol;
    u16* lA = &As[w * 1024];
    u16* lB = &Bs[w * 1024];

    const u32 fsw = (u32)((g ^ ((ml >> 1) & 3)) * 8);

    for (u32 k0 = 0; k0 < K; k0 += 32) {
        __syncthreads();
        gld_lds16(gA + k0, lA);
        gld_lds16(gA + 16 * K + k0, lA + 512);
        gld_lds16(gB + k0, lB);
        gld_lds16(gB + 16 * K + k0, lB + 512);
        __syncthreads();

        short8 af[4], bf[4];
#pragma unroll
        for (int it = 0; it < 4; ++it)
            af[it] = *(const short8*)&As[(wr * 64 + it * 16 + ml) * 32 + fsw];
#pragma unroll
        for (int ct = 0; ct < 4; ++ct)
            bf[ct] = *(const short8*)&Bs[(wc * 64 + ct * 16 + ml) * 32 + fsw];
#pragma unroll
        for (int it = 0; it < 4; ++it)
#pragma unroll
            for (int ct = 0; ct < 4; ++ct)
                acc[it][ct] = __builtin_amdgcn_mfma_f32_16x16x32_bf16(
                    af[it], bf[ct], acc[it][ct], 0, 0, 0);
    }

    if (MODE == 3) {
#pragma unroll
        for (int ct = 0; ct < 4; ++ct) {
            const u32 col = bn + wc * 64 + ct * 16 + ml;
            u16* dst = (u16*)C + (col >> 11) * 2097152 + (col & 2047);
#pragma unroll
            for (int it = 0; it < 4; ++it) {
                const u32 row = bm + wr * 64 + it * 16 + g * 4;
#pragma unroll
                for (int r = 0; r < 4; ++r)
                    dst[(size_t)(row + r) * 2048] = f2b(acc[it][ct][r]);
            }
        }
    } else {
#pragma unroll
        for (int ct = 0; ct < 4; ++ct) {
            const u32 col = bn + wc * 64 + ct * 16 + ml;
            const float bv = (MODE == 2 && bias) ? bias[col] : 0.0f;
#pragma unroll
            for (int it = 0; it < 4; ++it) {
                const u32 row = bm + wr * 64 + it * 16 + g * 4;
#pragma unroll
                for (int r = 0; r < 4; ++r) {
                    const float v = acc[it][ct][r] * scale + bv;
                    if (MODE == 2) ((float*)C)[(size_t)(row + r) * 1024 + col] = v;
                    else           ((u16*)C)[(size_t)(row + r) * 1024 + col] = f2b(v);
                }
            }
        }
    }
}

__global__ __launch_bounds__(256) void proj3_kernel(
    const u16* kb, const u16* qb, const u16* vb,
    const u16* Wkb, const u16* Wqb, const u16* Wvb,
    u16* Kp, u16* Qp, u16* Vt)
{
    if (blockIdx.z == 0)
        gemm_core<0>(kb, Wkb, Kp, nullptr, 1.0f, blockIdx.y * 128, blockIdx.x * 128);
    else if (blockIdx.z == 1)
        gemm_core<0>(qb, Wqb, Qp, nullptr, 0.18033688011112042f, blockIdx.y * 128, blockIdx.x * 128);
    else
        gemm_core<3>(Wvb, vb, Vt, nullptr, 1.0f, blockIdx.x * 128, blockIdx.y * 128);
}

// ---------------------------------------------------------------------------
// OUT GEMM (round-5 proven): 64x128 tile, grid (8, 64) = 512 blocks (2/CU).
// Wave w: rows (w>>1)*32..+31, cols (w&1)*64..+63 -> acc[2][4].
// ---------------------------------------------------------------------------
__global__ __launch_bounds__(256) void out_gemm_kernel(
    const u16* __restrict__ A, const u16* __restrict__ W,
    float* __restrict__ C, const float* __restrict__ bias)
{
    constexpr u32 K = 1024;
    __shared__ u16 As[64 * 32];
    __shared__ u16 Bs[128 * 32];

    const int tid  = threadIdx.x;
    const int lane = tid & 63;
    const int w    = tid >> 6;
    const int wr   = w >> 1, wc = w & 1;
    const int ml   = lane & 15, g = lane >> 4;
    const u32 bm   = blockIdx.y * 64, bn = blockIdx.x * 128;

    f32x4 acc[2][4] = {};

    const u32 scol = (u32)(((lane & 3) ^ ((lane >> 3) & 3)) * 8);
    const u16* gA = A + (size_t)(bm + w * 16 + (lane >> 2)) * K + scol;
    const u16* gB = W + (size_t)(bn + w * 32 + (lane >> 2)) * K + scol;
    u16* lA = &As[w * 512];
    u16* lB = &Bs[w * 1024];

    const u32 fsw = (u32)((g ^ ((ml >> 1) & 3)) * 8);

    for (u32 k0 = 0; k0 < K; k0 += 32) {
        __syncthreads();
        gld_lds16(gA + k0, lA);
        gld_lds16(gB + k0, lB);
        gld_lds16(gB + 16 * K + k0, lB + 512);
        __syncthreads();

        short8 af[2], bf[4];
#pragma unroll
        for (int it = 0; it < 2; ++it)
            af[it] = *(const short8*)&As[(wr * 32 + it * 16 + ml) * 32 + fsw];
#pragma unroll
        for (int ct = 0; ct < 4; ++ct)
            bf[ct] = *(const short8*)&Bs[(wc * 64 + ct * 16 + ml) * 32 + fsw];
#pragma unroll
        for (int it = 0; it < 2; ++it)
#pragma unroll
            for (int ct = 0; ct < 4; ++ct)
                acc[it][ct] = __builtin_amdgcn_mfma_f32_16x16x32_bf16(
                    af[it], bf[ct], acc[it][ct], 0, 0, 0);
    }

#pragma unroll
    for (int ct = 0; ct < 4; ++ct) {
        const u32 col = bn + wc * 64 + ct * 16 + ml;
        const float bv = bias ? bias[col] : 0.0f;
#pragma unroll
        for (int it = 0; it < 2; ++it) {
            const u32 row = bm + wr * 32 + it * 16 + g * 4;
#pragma unroll
            for (int r = 0; r < 4; ++r)
                C[(size_t)(row + r) * 1024 + col] = acc[it][ct][r] + bv;
        }
    }
}

// ---------------------------------------------------------------------------
// Flash attention v11 (round-8 proven, 49.9 us): 128-q blocks, 8 waves,
// double-buffered K/V DMA, bijective XCD swizzle, setprio(1) around compute.
// ---------------------------------------------------------------------------
__global__ __launch_bounds__(512, 4) void attn_kernel(
    const u16* __restrict__ Qp, const u16* __restrict__ Kp,
    const u16* __restrict__ Vt, u16* __restrict__ Op)
{
    __shared__ u16   Ks[2 * 4096];   // dbuf x [64 s][64 d], 16 KB
    __shared__ u16   Vs[2 * 4096];   // dbuf x [64 d][64 s], 16 KB
    __shared__ u16   Ps[8 * 1280];   // per-wave 32 q x (32 s + 8 pad), 20 KB
    __shared__ float Ls[4][32];

    const int tid  = threadIdx.x;
    const int lane = tid & 63;
    const int w    = tid >> 6;        // 0..7
    const int wq   = w >> 1;          // q-quarter owner (32 rows)
    const int ws   = w & 1;           // s-half of each 64-s step
    const int ml   = lane & 15;
    const int g    = lane >> 4;

    const u32 fid  = blockIdx.x + (blockIdx.y << 4);
    const u32 swz  = (fid & 7) * 64 + (fid >> 3);
    const u32 bh   = swz >> 4;
    const u32 t0   = (swz & 15) * 128;
    const u32 b    = bh >> 4, h = bh & 15;

    const u32 base  = b * 2048 * 1024 + h * 64;
    const u32 vbase = bh * 64 * 2048;

    short8 bq[2][2];
#pragma unroll
    for (int qt = 0; qt < 2; ++qt) {
        const u16* qr = Qp + base + (t0 + wq * 32 + qt * 16 + ml) * 1024 + g * 8;
        bq[qt][0] = *(const short8*)qr;
        bq[qt][1] = *(const short8*)(qr + 32);
    }

    f32x4 oacc[4][2] = {};
    float l4[2] = {};

    const u32 srow = (u32)(lane >> 3);
    const u32 schk = (u32)((lane & 7) ^ (lane >> 3));
    const u16* gK = Kp + base + (size_t)(w * 8 + srow) * 1024 + schk * 8;
    const u16* gV = Vt + vbase + (size_t)(w * 8 + srow) * 2048 + schk * 8;
    u16* lK0 = &Ks[w * 512];
    u16* lK1 = &Ks[4096 + w * 512];
    u16* lV0 = &Vs[w * 512];
    u16* lV1 = &Vs[4096 + w * 512];

    const u32 kaOff = (u32)((ws * 32 + ml) * 64 + ((g ^ (ml & 7)) * 8));
    const u32 vaOff = (u32)(ml * 64 + (((ws * 4 + g) ^ (ml & 7)) * 8));
    u16* Pw  = &Ps[w * 1280];
    u32* PwU = (u32*)Pw;
    const u32 pWr = (u32)(ml * 20 + g * 2);    // + qt*320 + sub*8   (u32)
    const u32 pRd = (u32)(ml * 40 + g * 8);    // + qt*640           (u16)

#define ATTN_STAGE(KD, VD)                                                   \
    { gld_lds16(gK, (KD)); gld_lds16(gV, (VD)); gK += 65536; gV += 64; }

#define ATTN_COMPUTE(KB, VB)                                                 \
    {                                                                        \
        __builtin_amdgcn_s_setprio(1);                                       \
        short8 vv[4];                                                        \
        _Pragma("unroll")                                                    \
        for (int dt = 0; dt < 4; ++dt)                                       \
            vv[dt] = *(const short8*)&(VB)[vaOff + dt * 1024];               \
        _Pragma("unroll")                                                    \
        for (int sub = 0; sub < 2; ++sub) {                                  \
            short8 k0 = *(const short8*)&(KB)[kaOff + sub * 1024];           \
            short8 k1 = *(const short8*)&(KB)[(kaOff ^ 32) + sub * 1024];    \
            _Pragma("unroll")                                                \
            for (int qt = 0; qt < 2; ++qt) {                                 \
                f32x4 z = {};                                                \
                z = __builtin_amdgcn_mfma_f32_16x16x32_bf16(                 \
                    k0, bq[qt][0], z, 0, 0, 0);                              \
                z = __builtin_amdgcn_mfma_f32_16x16x32_bf16(                 \
                    k1, bq[qt][1], z, 0, 0, 0);                              \
                const float p0 = fexp2(z[0]), p1 = fexp2(z[1]);              \
                const float p2 = fexp2(z[2]), p3 = fexp2(z[3]);              \
                l4[qt] += (p0 + p1) + (p2 + p3);                             \
                uint2 pv; pv.x = pack2(p0, p1); pv.y = pack2(p2, p3);        \
                *(uint2*)&PwU[pWr + (u32)(qt * 320 + sub * 8)] = pv;         \
            }                                                                \
        }                                                                    \
        _Pragma("unroll")                                                    \
        for (int qt = 0; qt < 2; ++qt) {                                     \
            short8 pb = *(const short8*)&Pw[pRd + (u32)(qt * 640)];          \
            _Pragma("unroll")                                                \
            for (int dt = 0; dt < 4; ++dt)                                   \
                oacc[dt][qt] = __builtin_amdgcn_mfma_f32_16x16x32_bf16(      \
                    vv[dt], pb, oacc[dt][qt], 0, 0, 0);                      \
        }                                                                    \
        __builtin_amdgcn_s_setprio(0);                                       \
    }

    ATTN_STAGE(lK0, lV0)
    __syncthreads();

#pragma unroll 1
    for (int it = 0; it < 16; ++it) {
        ATTN_STAGE(lK1, lV1)
        ATTN_COMPUTE(Ks, Vs)
        __syncthreads();
        if (it < 15) ATTN_STAGE(lK0, lV0)
        ATTN_COMPUTE(Ks + 4096, Vs + 4096)
        __syncthreads();
    }
#undef ATTN_STAGE
#undef ATTN_COMPUTE

#pragma unroll
    for (int qt = 0; qt < 2; ++qt) {
        l4[qt] += __shfl_xor(l4[qt], 16);
        l4[qt] += __shfl_xor(l4[qt], 32);
    }

    float* Rw = (wq < 2) ? ((float*)Ks + wq * 2048) : ((float*)Vs + (wq - 2) * 2048);
    if (ws == 1) {
#pragma unroll
        for (int dt = 0; dt < 4; ++dt)
#pragma unroll
            for (int qt = 0; qt < 2; ++qt)
#pragma unroll
                for (int r = 0; r < 4; ++r)
                    Rw[(dt * 16 + g * 4 + r) * 32 + qt * 16 + ml] = oacc[dt][qt][r];
        if (g == 0) {
#pragma unroll
            for (int qt = 0; qt < 2; ++qt) Ls[wq][qt * 16 + ml] = l4[qt];
        }
    }
    __syncthreads();
    if (ws == 0) {
#pragma unroll
        for (int dt = 0; dt < 4; ++dt)
#pragma unroll
            for (int qt = 0; qt < 2; ++qt)
#pragma unroll
                for (int r = 0; r < 4; ++r)
                    oacc[dt][qt][r] += Rw[(dt * 16 + g * 4 + r) * 32 + qt * 16 + ml];
#pragma unroll
        for (int qt = 0; qt < 2; ++qt) {
            const u32 q = (u32)(wq * 32 + qt * 16 + ml);
            const float inv = 1.0f / (l4[qt] + Ls[wq][qt * 16 + ml]);
            const u32 row = (b * 2048 + t0 + q) * 1024 + h * 64;
#pragma unroll
            for (int dt = 0; dt < 4; ++dt) {
                const u32 ci = row + dt * 16 + g * 4;
                *(u32*)&Op[ci]     = pack2(oacc[dt][qt][0] * inv, oacc[dt][qt][1] * inv);
                *(u32*)&Op[ci + 2] = pack2(oacc[dt][qt][2] * inv, oacc[dt][qt][3] * inv);
            }
        }
    }
}

extern "C" void kernel_launch(void* const* d_in, const int* in_sizes, int n_in,
                              void* d_out, int out_size, void* d_ws, size_t ws_size,
                              hipStream_t stream)
{
    const float* kin = (const float*)d_in[0];
    const float* qin = (const float*)d_in[1];
    const float* vin = (const float*)d_in[2];
    const float* Wk  = (const float*)d_in[3];
    const float* Wq  = (const float*)d_in[4];
    const float* Wv  = (const float*)d_in[5];
    const float* Wo  = (const float*)d_in[6];
    const float* bo  = (const float*)d_in[7];
    float* out = (float*)d_out;

    const size_t ACT = 4194304;
    const size_t WSZ = 1048576;

    u16* kb  = (u16*)d_ws;
    u16* qb  = kb + ACT;
    u16* vb  = qb + ACT;
    u16* Wkb = vb + ACT;
    u16* Wqb = Wkb + WSZ;
    u16* Wvb = Wqb + WSZ;
    u16* Wob = Wvb + WSZ;
    u16* Kp  = Wob + WSZ;
    u16* Qp  = Kp + ACT;
    u16* Vt  = Qp + ACT;
    u16* Op  = kb;   // alias: kb consumed by proj3 before attn writes Op

    convert_kernel<<<dim3(1024, 7), 256, 0, stream>>>(
        kin, qin, vin, Wk, Wq, Wv, Wo, kb, qb, vb, Wkb, Wqb, Wvb, Wob);
    proj3_kernel<<<dim3(8, 32, 3), 256, 0, stream>>>(
        kb, qb, vb, Wkb, Wqb, Wvb, Kp, Qp, Vt);
    attn_kernel<<<dim3(16, 32), 512, 0, stream>>>(Qp, Kp, Vt, Op);
    out_gemm_kernel<<<dim3(8, 64), 256, 0, stream>>>(Op, Wob, out, bo);
}